// Round 2
// baseline (309.529 us; speedup 1.0000x reference)
//
#include <hip/hip_runtime.h>
#include <hip/hip_bf16.h>

#define NPTS 131072
#define DIM  512
#define HID  128
#define KCL  3
#define NPOSI 8192
#define NNEGI 8192
#define KM_ITERS 4

typedef __attribute__((ext_vector_type(8))) short bf16x8;
typedef __attribute__((ext_vector_type(4))) float f32x4;

// ws layout (float offsets)
enum {
  WS_SHIFT_POS = 0,      // 512
  WS_SHIFT_NEG = 512,    // 512
  WS_NEGSUM    = 1024,   // 512
  WS_CENTERS   = 1536,   // 1536
  WS_CNORM     = 3072,   // 3
  WS_COUNTS    = 3075,   // 3
  WS_SUMS      = 3080,   // 1536
  WS_PN        = 4616,   // 3
  WS_NN        = 4619,   // 1
  WS_PPROTO    = 4620,   // 1536
  WS_NPROTO    = 6156,   // 512
  WS_W1BF      = 6672,   // 65536 bf16 = 32768 float slots -> end 39440 floats (~158KB)
};

__device__ __forceinline__ short f2bf(float x) {
  __hip_bfloat16 h = __float2bfloat16(x);
  return *reinterpret_cast<short*>(&h);
}

// ---------------- zero accumulators ----------------
__global__ void k_zero(float* __restrict__ ws) {
  int idx = 1024 + blockIdx.x * 256 + threadIdx.x;
  if (idx < 4620) ws[idx] = 0.f;
}

// ---------------- calibration matvecs: shift = 0.15*(W @ ctx + b) ----------------
__global__ __launch_bounds__(256) void k_calib(const float* __restrict__ Wp, const float* __restrict__ bp,
                        const float* __restrict__ Wn, const float* __restrict__ bn,
                        const float* __restrict__ pos_ctx, const float* __restrict__ neg_ctx,
                        float* __restrict__ ws) {
  int b = blockIdx.x;            // 0..31 ; b>>4: 0 = pos, 1 = neg
  int mat = b >> 4;
  const float* W    = mat ? Wn : Wp;
  const float* bias = mat ? bn : bp;
  const float* ctx  = mat ? neg_ctx : pos_ctx;
  float* outp = ws + (mat ? WS_SHIFT_NEG : WS_SHIFT_POS);
  int t = threadIdx.x;
  int row = (b & 15) * 32 + (t >> 3);
  int sub = t & 7;               // 8 threads per row, 64 elems each
  const float* wr = W + row * DIM + sub * 64;
  const float* cr = ctx + sub * 64;
  float s = 0.f;
#pragma unroll
  for (int j = 0; j < 64; j += 4) {
    float4 w4 = *(const float4*)(wr + j);
    float4 c4 = *(const float4*)(cr + j);
    s += w4.x * c4.x + w4.y * c4.y + w4.z * c4.z + w4.w * c4.w;
  }
  s += __shfl_xor(s, 1);
  s += __shfl_xor(s, 2);
  s += __shfl_xor(s, 4);
  if (sub == 0) outp[row] = 0.15f * (s + bias[row]);
}

// ---------------- neg gather-mean accumulate ----------------
__global__ __launch_bounds__(256) void k_negmean(const float* __restrict__ zp,
                                                 const int* __restrict__ neg_idx,
                                                 float* __restrict__ ws) {
  int t = threadIdx.x;
  int c0 = t * 2;
  float a0 = 0.f, a1 = 0.f;
  int j0 = blockIdx.x * 64;      // 128 blocks x 64 rows = 8192
  for (int j = 0; j < 64; ++j) {
    int row = neg_idx[j0 + j];
    float2 v = *(const float2*)(zp + (size_t)row * DIM + c0);
    a0 += v.x; a1 += v.y;
  }
  atomicAdd(&ws[WS_NEGSUM + c0],     a0);
  atomicAdd(&ws[WS_NEGSUM + c0 + 1], a1);
}

// ---------------- kmeans init: centers = x[pos_idx[{0,4095,8191}]] ----------------
__global__ __launch_bounds__(256) void k_init_centers(const float* __restrict__ zp,
                                                      const int* __restrict__ pos_idx,
                                                      float* __restrict__ ws) {
  __shared__ float cc[KCL * DIM];
  int t = threadIdx.x;
  for (int idx = t; idx < KCL * DIM; idx += 256) {
    int k = idx >> 9, d = idx & 511;
    int sel = (k == 0) ? 0 : ((k == 1) ? 4095 : 8191);
    float v = zp[(size_t)pos_idx[sel] * DIM + d];
    ws[WS_CENTERS + idx] = v;
    cc[idx] = v;
  }
  __syncthreads();
  int w = t >> 6, l = t & 63;
  if (w < KCL) {
    float s = 0.f;
#pragma unroll
    for (int m = 0; m < 8; ++m) { float v = cc[w * DIM + l + m * 64]; s += v * v; }
#pragma unroll
    for (int m = 1; m < 64; m <<= 1) s += __shfl_xor(s, m);
    if (l == 0) ws[WS_CNORM + w] = s;
  }
}

// ---------------- kmeans assignment + accumulate ----------------
__global__ __launch_bounds__(256) void k_assign(const float* __restrict__ zp,
                                                const int* __restrict__ pos_idx,
                                                float* __restrict__ ws) {
  __shared__ float lsum[KCL * DIM];
  __shared__ float lcnt[KCL];
  int t = threadIdx.x, w = t >> 6, l = t & 63;
  for (int idx = t; idx < KCL * DIM; idx += 256) lsum[idx] = 0.f;
  if (t < KCL) lcnt[t] = 0.f;

  float ck0[8], ck1[8], ck2[8];
#pragma unroll
  for (int j = 0; j < 8; ++j) {
    ck0[j] = ws[WS_CENTERS + 0 * DIM + l * 8 + j];
    ck1[j] = ws[WS_CENTERS + 1 * DIM + l * 8 + j];
    ck2[j] = ws[WS_CENTERS + 2 * DIM + l * 8 + j];
  }
  float cn0 = ws[WS_CNORM + 0], cn1 = ws[WS_CNORM + 1], cn2 = ws[WS_CNORM + 2];
  float acc0[8] = {0,0,0,0,0,0,0,0}, acc1[8] = {0,0,0,0,0,0,0,0}, acc2[8] = {0,0,0,0,0,0,0,0};
  float cnt0 = 0.f, cnt1 = 0.f, cnt2 = 0.f;
  __syncthreads();

  int wid = blockIdx.x * 4 + w;  // 128 blocks * 4 waves = 512 waves
  for (int p = wid; p < NPOSI; p += 512) {
    int row = pos_idx[p];
    const float* xr = zp + (size_t)row * DIM + l * 8;
    float4 x0 = *(const float4*)(xr);
    float4 x1 = *(const float4*)(xr + 4);
    float x[8] = {x0.x, x0.y, x0.z, x0.w, x1.x, x1.y, x1.z, x1.w};
    float d0 = 0.f, d1 = 0.f, d2 = 0.f;
#pragma unroll
    for (int j = 0; j < 8; ++j) { d0 += x[j] * ck0[j]; d1 += x[j] * ck1[j]; d2 += x[j] * ck2[j]; }
#pragma unroll
    for (int m = 1; m < 64; m <<= 1) {
      d0 += __shfl_xor(d0, m); d1 += __shfl_xor(d1, m); d2 += __shfl_xor(d2, m);
    }
    float t0 = cn0 - 2.f * d0, t1 = cn1 - 2.f * d1, t2 = cn2 - 2.f * d2;
    int a = 0; float best = t0;
    if (t1 < best) { best = t1; a = 1; }
    if (t2 < best) { best = t2; a = 2; }
    if (a == 0)      { cnt0 += 1.f;
#pragma unroll
      for (int j = 0; j < 8; ++j) acc0[j] += x[j]; }
    else if (a == 1) { cnt1 += 1.f;
#pragma unroll
      for (int j = 0; j < 8; ++j) acc1[j] += x[j]; }
    else             { cnt2 += 1.f;
#pragma unroll
      for (int j = 0; j < 8; ++j) acc2[j] += x[j]; }
  }
#pragma unroll
  for (int j = 0; j < 8; ++j) {
    atomicAdd(&lsum[0 * DIM + l * 8 + j], acc0[j]);
    atomicAdd(&lsum[1 * DIM + l * 8 + j], acc1[j]);
    atomicAdd(&lsum[2 * DIM + l * 8 + j], acc2[j]);
  }
  if (l == 0) {
    atomicAdd(&lcnt[0], cnt0); atomicAdd(&lcnt[1], cnt1); atomicAdd(&lcnt[2], cnt2);
  }
  __syncthreads();
  for (int idx = t; idx < KCL * DIM; idx += 256) atomicAdd(&ws[WS_SUMS + idx], lsum[idx]);
  if (t < KCL) atomicAdd(&ws[WS_COUNTS + t], lcnt[t]);
}

// ---------------- kmeans center update (+ re-zero accumulators) ----------------
__global__ __launch_bounds__(256) void k_update(float* __restrict__ ws) {
  __shared__ float cc[KCL * DIM];
  int t = threadIdx.x;
  float c0 = ws[WS_COUNTS + 0], c1 = ws[WS_COUNTS + 1], c2 = ws[WS_COUNTS + 2];
  __syncthreads();   // all counts read before anyone zeroes them
  for (int idx = t; idx < KCL * DIM; idx += 256) {
    int k = idx >> 9;
    float cnt = (k == 0) ? c0 : ((k == 1) ? c1 : c2);
    float v = (cnt > 0.f) ? ws[WS_SUMS + idx] / cnt : ws[WS_CENTERS + idx];
    ws[WS_CENTERS + idx] = v;
    cc[idx] = v;
    ws[WS_SUMS + idx] = 0.f;
  }
  if (t < KCL) ws[WS_COUNTS + t] = 0.f;
  __syncthreads();
  int w = t >> 6, l = t & 63;
  if (w < KCL) {
    float s = 0.f;
#pragma unroll
    for (int m = 0; m < 8; ++m) { float v = cc[w * DIM + l + m * 64]; s += v * v; }
#pragma unroll
    for (int m = 1; m < 64; m <<= 1) s += __shfl_xor(s, m);
    if (l == 0) ws[WS_CNORM + w] = s;
  }
}

// ---------------- finalize prototypes, norms, write proto outputs (float32) ----------------
__global__ __launch_bounds__(256) void k_finalize(float* __restrict__ ws, float* __restrict__ out) {
  __shared__ float pp[KCL * DIM];
  __shared__ float np[DIM];
  int t = threadIdx.x;
  for (int idx = t; idx < KCL * DIM; idx += 256) {
    int d = idx & 511;
    float v = ws[WS_CENTERS + idx] + ws[WS_SHIFT_POS + d];
    ws[WS_PPROTO + idx] = v;
    pp[idx] = v;
    out[7 * NPTS + idx] = v;
  }
  for (int d = t; d < DIM; d += 256) {
    float v = ws[WS_NEGSUM + d] * (1.f / NNEGI) + ws[WS_SHIFT_NEG + d];
    ws[WS_NPROTO + d] = v;
    np[d] = v;
    out[7 * NPTS + KCL * DIM + d] = v;
  }
  __syncthreads();
  int w = t >> 6, l = t & 63;
  float s = 0.f;
  if (w < KCL) {
#pragma unroll
    for (int m = 0; m < 8; ++m) { float v = pp[w * DIM + l + m * 64]; s += v * v; }
  } else {
#pragma unroll
    for (int m = 0; m < 8; ++m) { float v = np[l + m * 64]; s += v * v; }
  }
#pragma unroll
  for (int m = 1; m < 64; m <<= 1) s += __shfl_xor(s, m);
  if (l == 0) {
    if (w < KCL) ws[WS_PN + w] = s; else ws[WS_NN] = s;
  }
}

// ---------------- W1 -> bf16 ----------------
__global__ __launch_bounds__(256) void k_w1conv(const float* __restrict__ W1, float* __restrict__ ws) {
  int i = blockIdx.x * 256 + threadIdx.x;   // 256 blocks -> 65536
  __hip_bfloat16* dst = (__hip_bfloat16*)(ws + WS_W1BF);
  dst[i] = __float2bfloat16(W1[i]);
}

// ---------------- cls head: cls_logit = relu(z@W1^T + b1) @ W2^T + b2 (MFMA) ----------------
// writes cls_logit into out[0..N) (the logits slot); k_proto overwrites it with final logits
__global__ __launch_bounds__(256) void k_cls(const float* __restrict__ zc,
                                             const float* __restrict__ b1,
                                             const float* __restrict__ W2,
                                             const float* __restrict__ b2,
                                             const float* __restrict__ ws,
                                             float* __restrict__ out) {
  __shared__ __hip_bfloat16 Bs[HID][40];   // padded to 40 to spread banks
  const __hip_bfloat16* W1bf = (const __hip_bfloat16*)(ws + WS_W1BF);
  int t = threadIdx.x, w = t >> 6, l = t & 63;
  int m0 = blockIdx.x * 64;                // 2048 blocks
  f32x4 acc[8];
#pragma unroll
  for (int n = 0; n < 8; ++n) acc[n] = (f32x4){0.f, 0.f, 0.f, 0.f};

  int arow = m0 + w * 16 + (l & 15);
  const float* aptr = zc + (size_t)arow * DIM + (l >> 4) * 8;
  int srow = t >> 1, scol = (t & 1) * 16;  // B staging: 128 rows x 32 cols bf16

  for (int kc = 0; kc < DIM; kc += 32) {
    __syncthreads();
    {
      const float4* src = (const float4*)(W1bf + (size_t)srow * DIM + kc + scol);
      float4 v0 = src[0], v1 = src[1];
      *(float4*)(&Bs[srow][scol])     = v0;
      *(float4*)(&Bs[srow][scol + 8]) = v1;
    }
    __syncthreads();
    float4 a0 = *(const float4*)(aptr + kc);
    float4 a1 = *(const float4*)(aptr + kc + 4);
    bf16x8 af;
    af[0] = f2bf(a0.x); af[1] = f2bf(a0.y); af[2] = f2bf(a0.z); af[3] = f2bf(a0.w);
    af[4] = f2bf(a1.x); af[5] = f2bf(a1.y); af[6] = f2bf(a1.z); af[7] = f2bf(a1.w);
#pragma unroll
    for (int n = 0; n < 8; ++n) {
      bf16x8 bf = *(const bf16x8*)(&Bs[n * 16 + (l & 15)][(l >> 4) * 8]);
      acc[n] = __builtin_amdgcn_mfma_f32_16x16x32_bf16(af, bf, acc[n], 0, 0, 0);
    }
  }
  // epilogue: h = relu(acc + b1); partial = sum over cols h*W2
  float p[4] = {0.f, 0.f, 0.f, 0.f};
  int col_l = l & 15;
#pragma unroll
  for (int n = 0; n < 8; ++n) {
    int col = n * 16 + col_l;
    float bb = b1[col], w2 = W2[col];
#pragma unroll
    for (int r = 0; r < 4; ++r) {
      float h = acc[n][r] + bb;
      h = h > 0.f ? h : 0.f;
      p[r] += h * w2;
    }
  }
#pragma unroll
  for (int m = 1; m < 16; m <<= 1) {
#pragma unroll
    for (int r = 0; r < 4; ++r) p[r] += __shfl_xor(p[r], m);
  }
  if (col_l == 0) {
    float bias2 = b2[0];
    int rbase = m0 + w * 16 + (l >> 4) * 4;
#pragma unroll
    for (int r = 0; r < 4; ++r) out[rbase + r] = p[r] + bias2;
  }
}

// ---------------- distance pass + fused epilogue (float32 outputs) ----------------
__global__ __launch_bounds__(256) void k_proto(const float* __restrict__ zp,
                                               const float* __restrict__ ws,
                                               float* out) {
  int t = threadIdx.x, w = t >> 6, l = t & 63;
  float pp0[8], pp1[8], pp2[8], np[8];
#pragma unroll
  for (int j = 0; j < 8; ++j) {
    pp0[j] = ws[WS_PPROTO + 0 * DIM + l * 8 + j];
    pp1[j] = ws[WS_PPROTO + 1 * DIM + l * 8 + j];
    pp2[j] = ws[WS_PPROTO + 2 * DIM + l * 8 + j];
    np[j]  = ws[WS_NPROTO + l * 8 + j];
  }
  float pn0 = ws[WS_PN + 0], pn1 = ws[WS_PN + 1], pn2 = ws[WS_PN + 2], nn = ws[WS_NN];

  int wid = blockIdx.x * 4 + w;   // 2048 blocks * 4 waves = 8192 waves
  for (int i = wid; i < NPTS; i += 8192) {
    const float* xr = zp + (size_t)i * DIM + l * 8;
    float4 x0 = *(const float4*)(xr);
    float4 x1 = *(const float4*)(xr + 4);
    float x[8] = {x0.x, x0.y, x0.z, x0.w, x1.x, x1.y, x1.z, x1.w};
    float sx = 0.f, d0 = 0.f, d1 = 0.f, d2 = 0.f, dn = 0.f;
#pragma unroll
    for (int j = 0; j < 8; ++j) {
      sx += x[j] * x[j];
      d0 += x[j] * pp0[j];
      d1 += x[j] * pp1[j];
      d2 += x[j] * pp2[j];
      dn += x[j] * np[j];
    }
#pragma unroll
    for (int m = 1; m < 64; m <<= 1) {
      sx += __shfl_xor(sx, m);
      d0 += __shfl_xor(d0, m);
      d1 += __shfl_xor(d1, m);
      d2 += __shfl_xor(d2, m);
      dn += __shfl_xor(dn, m);
    }
    float e0 = sx + pn0 - 2.f * d0; e0 = e0 > 0.f ? e0 : 0.f;
    float e1 = sx + pn1 - 2.f * d1; e1 = e1 > 0.f ? e1 : 0.f;
    float e2 = sx + pn2 - 2.f * d2; e2 = e2 > 0.f ? e2 : 0.f;
    float dpos = e0; int a = 0;
    if (e1 < dpos) { dpos = e1; a = 1; }
    if (e2 < dpos) { dpos = e2; a = 2; }
    float dneg = (sx + nn - 2.f * dn) * (1.f / DIM);
    float plog = (dneg - dpos) * 0.04419417382415922f;  // 1/sqrt(512)
    float o2 = 0.2f * plog;
    float cls = out[i];                                 // written by k_cls
    float lg = (cls + o2) * 0.4f;                       // /2.5
    float prob = 1.f / (1.f + expf(-lg));
    if (l == 0)      out[i]            = lg;
    else if (l == 1) out[NPTS + i]     = prob;
    else if (l == 2) out[2 * NPTS + i] = o2;
    else if (l == 3) out[3 * NPTS + i] = (float)a;
    else if (l == 4) out[4 * NPTS + 3 * i + 0] = e0;
    else if (l == 5) out[4 * NPTS + 3 * i + 1] = e1;
    else if (l == 6) out[4 * NPTS + 3 * i + 2] = e2;
  }
}

extern "C" void kernel_launch(void* const* d_in, const int* in_sizes, int n_in,
                              void* d_out, int out_size, void* d_ws, size_t ws_size,
                              hipStream_t stream) {
  const float* z_cls   = (const float*)d_in[0];
  const float* z_proto = (const float*)d_in[1];
  const float* pos_ctx = (const float*)d_in[2];
  const float* neg_ctx = (const float*)d_in[3];
  const float* W1      = (const float*)d_in[4];
  const float* b1      = (const float*)d_in[5];
  const float* W2      = (const float*)d_in[6];
  const float* b2      = (const float*)d_in[7];
  const float* Wp      = (const float*)d_in[8];
  const float* bp      = (const float*)d_in[9];
  const float* Wn      = (const float*)d_in[10];
  const float* bn      = (const float*)d_in[11];
  const int* pos_idx   = (const int*)d_in[12];
  const int* neg_idx   = (const int*)d_in[13];
  float* out           = (float*)d_out;
  float* ws            = (float*)d_ws;

  k_zero<<<15, 256, 0, stream>>>(ws);
  k_w1conv<<<256, 256, 0, stream>>>(W1, ws);
  k_calib<<<32, 256, 0, stream>>>(Wp, bp, Wn, bn, pos_ctx, neg_ctx, ws);
  k_negmean<<<128, 256, 0, stream>>>(z_proto, neg_idx, ws);
  k_init_centers<<<1, 256, 0, stream>>>(z_proto, pos_idx, ws);
  for (int it = 0; it < KM_ITERS; ++it) {
    k_assign<<<128, 256, 0, stream>>>(z_proto, pos_idx, ws);
    k_update<<<1, 256, 0, stream>>>(ws);
  }
  k_finalize<<<1, 256, 0, stream>>>(ws, out);
  k_cls<<<NPTS / 64, 256, 0, stream>>>(z_cls, b1, W2, b2, ws, out);
  k_proto<<<2048, 256, 0, stream>>>(z_proto, ws, out);
}

// Round 3
// 294.637 us; speedup vs baseline: 1.0505x; 1.0505x over previous
//
#include <hip/hip_runtime.h>
#include <hip/hip_bf16.h>

#define NPTS 131072
#define DIM  512
#define HID  128
#define KCL  3
#define NPOSI 8192
#define NNEGI 8192

typedef __attribute__((ext_vector_type(8))) short bf16x8;
typedef __attribute__((ext_vector_type(4))) float f32x4;

// ws layout (float offsets)
enum {
  WS_SHIFT_POS = 0,       // 512
  WS_SHIFT_NEG = 512,     // 512
  WS_NEGSUM    = 1024,    // 512  (written by k_km<0> block 128)
  WS_NEGPART   = 1536,    // 128*512 = 65536 -> ends 67072
  WS_SUMS      = 67072,   // 4 iters * 1539 (3*512 sums + 3 counts) -> ends 73228
  WS_W1BF      = 73228,   // 65536 bf16 = 32768 float slots -> ends 105996 (~424KB total)
};
#define SUMS_STRIDE 1539

__device__ __forceinline__ short f2bf(float x) {
  __hip_bfloat16 h = __float2bfloat16(x);
  return *reinterpret_cast<short*>(&h);
}

// ================= k_prep: W1->bf16 | calib matvecs | negmean partials | zero sums =================
__global__ __launch_bounds__(256) void k_prep(const float* __restrict__ W1,
                                              const float* __restrict__ Wp, const float* __restrict__ bp,
                                              const float* __restrict__ Wn, const float* __restrict__ bn,
                                              const float* __restrict__ pos_ctx, const float* __restrict__ neg_ctx,
                                              const float* __restrict__ zp, const int* __restrict__ neg_idx,
                                              float* __restrict__ ws) {
  int bid = blockIdx.x, t = threadIdx.x;
  if (bid < 256) {
    // W1 -> bf16
    int i = bid * 256 + t;
    __hip_bfloat16* dst = (__hip_bfloat16*)(ws + WS_W1BF);
    dst[i] = __float2bfloat16(W1[i]);
  } else if (bid < 288) {
    // calibration matvec: shift = 0.15*(W @ ctx + b)
    int b = bid - 256;           // 0..31
    int mat = b >> 4;
    const float* W    = mat ? Wn : Wp;
    const float* bias = mat ? bn : bp;
    const float* ctx  = mat ? neg_ctx : pos_ctx;
    float* outp = ws + (mat ? WS_SHIFT_NEG : WS_SHIFT_POS);
    int row = (b & 15) * 32 + (t >> 3);
    int sub = t & 7;
    const float* wr = W + row * DIM + sub * 64;
    const float* cr = ctx + sub * 64;
    float s = 0.f;
#pragma unroll
    for (int j = 0; j < 64; j += 4) {
      float4 w4 = *(const float4*)(wr + j);
      float4 c4 = *(const float4*)(cr + j);
      s += w4.x * c4.x + w4.y * c4.y + w4.z * c4.z + w4.w * c4.w;
    }
    s += __shfl_xor(s, 1);
    s += __shfl_xor(s, 2);
    s += __shfl_xor(s, 4);
    if (sub == 0) outp[row] = 0.15f * (s + bias[row]);
  } else if (bid < 416) {
    // neg gather-mean partials (no atomics, no pre-zero needed)
    int j = bid - 288;           // 0..127
    int c0 = t * 2;
    float a0 = 0.f, a1 = 0.f;
    int j0 = j * 64;
    for (int jj = 0; jj < 64; ++jj) {
      int row = neg_idx[j0 + jj];
      float2 v = *(const float2*)(zp + (size_t)row * DIM + c0);
      a0 += v.x; a1 += v.y;
    }
    ws[WS_NEGPART + j * DIM + c0]     = a0;
    ws[WS_NEGPART + j * DIM + c0 + 1] = a1;
  } else {
    // zero the 4 per-iteration sum/count buffers (consumed only by later kernels)
    for (int idx = t; idx < 4 * SUMS_STRIDE; idx += 256) ws[WS_SUMS + idx] = 0.f;
  }
}

// ================= k_km<IT>: recompute center chain, assign, accumulate =================
template <int IT>
__global__ __launch_bounds__(256) void k_km(const float* __restrict__ zp,
                                            const int* __restrict__ pos_idx,
                                            float* __restrict__ ws) {
  int bid = blockIdx.x, t = threadIdx.x;
  if (IT == 0 && bid == 128) {
    // reduce negmean partials -> NEGSUM
    int c0 = t * 2;
    float a0 = 0.f, a1 = 0.f;
#pragma unroll 8
    for (int j = 0; j < 128; ++j) {
      float2 v = *(const float2*)(ws + WS_NEGPART + j * DIM + c0);
      a0 += v.x; a1 += v.y;
    }
    ws[WS_NEGSUM + c0]     = a0;
    ws[WS_NEGSUM + c0 + 1] = a1;
    return;
  }
  __shared__ float cc[KCL * DIM];
  __shared__ float cn[KCL];
  __shared__ float lsum[KCL * DIM];
  __shared__ float lcnt[KCL];
  int w = t >> 6, l = t & 63;

  for (int idx = t; idx < KCL * DIM; idx += 256) lsum[idx] = 0.f;
  if (t < KCL) lcnt[t] = 0.f;

  // center chain: init = gathered rows, then IT refinement steps from sum buffers
  for (int idx = t; idx < KCL * DIM; idx += 256) {
    int k = idx >> 9;
    int sel = (k == 0) ? 0 : ((k == 1) ? 4095 : 8191);
    float v = zp[(size_t)pos_idx[sel] * DIM + (idx & 511)];
#pragma unroll
    for (int j = 0; j < IT; ++j) {
      float cntv = ws[WS_SUMS + j * SUMS_STRIDE + 3 * DIM + k];
      float sv   = ws[WS_SUMS + j * SUMS_STRIDE + idx];
      v = (cntv > 0.f) ? sv / cntv : v;
    }
    cc[idx] = v;
  }
  __syncthreads();
  if (w < KCL) {
    float s = 0.f;
#pragma unroll
    for (int m = 0; m < 8; ++m) { float v = cc[w * DIM + l + m * 64]; s += v * v; }
#pragma unroll
    for (int m = 1; m < 64; m <<= 1) s += __shfl_xor(s, m);
    if (l == 0) cn[w] = s;
  }
  __syncthreads();

  float ck0[8], ck1[8], ck2[8];
#pragma unroll
  for (int j = 0; j < 8; ++j) {
    ck0[j] = cc[0 * DIM + l * 8 + j];
    ck1[j] = cc[1 * DIM + l * 8 + j];
    ck2[j] = cc[2 * DIM + l * 8 + j];
  }
  float cn0 = cn[0], cn1 = cn[1], cn2 = cn[2];
  float acc0[8] = {0,0,0,0,0,0,0,0}, acc1[8] = {0,0,0,0,0,0,0,0}, acc2[8] = {0,0,0,0,0,0,0,0};
  float cnt0 = 0.f, cnt1 = 0.f, cnt2 = 0.f;

  int wid = bid * 4 + w;   // 512 waves
  for (int p = wid; p < NPOSI; p += 512) {
    int row = pos_idx[p];
    const float* xr = zp + (size_t)row * DIM + l * 8;
    float4 x0 = *(const float4*)(xr);
    float4 x1 = *(const float4*)(xr + 4);
    float x[8] = {x0.x, x0.y, x0.z, x0.w, x1.x, x1.y, x1.z, x1.w};
    float d0 = 0.f, d1 = 0.f, d2 = 0.f;
#pragma unroll
    for (int j = 0; j < 8; ++j) { d0 += x[j] * ck0[j]; d1 += x[j] * ck1[j]; d2 += x[j] * ck2[j]; }
#pragma unroll
    for (int m = 1; m < 64; m <<= 1) {
      d0 += __shfl_xor(d0, m); d1 += __shfl_xor(d1, m); d2 += __shfl_xor(d2, m);
    }
    float t0 = cn0 - 2.f * d0, t1 = cn1 - 2.f * d1, t2 = cn2 - 2.f * d2;
    int a = 0; float best = t0;
    if (t1 < best) { best = t1; a = 1; }
    if (t2 < best) { best = t2; a = 2; }
    if (a == 0)      { cnt0 += 1.f;
#pragma unroll
      for (int j = 0; j < 8; ++j) acc0[j] += x[j]; }
    else if (a == 1) { cnt1 += 1.f;
#pragma unroll
      for (int j = 0; j < 8; ++j) acc1[j] += x[j]; }
    else             { cnt2 += 1.f;
#pragma unroll
      for (int j = 0; j < 8; ++j) acc2[j] += x[j]; }
  }
#pragma unroll
  for (int j = 0; j < 8; ++j) {
    atomicAdd(&lsum[0 * DIM + l * 8 + j], acc0[j]);
    atomicAdd(&lsum[1 * DIM + l * 8 + j], acc1[j]);
    atomicAdd(&lsum[2 * DIM + l * 8 + j], acc2[j]);
  }
  if (l == 0) {
    atomicAdd(&lcnt[0], cnt0); atomicAdd(&lcnt[1], cnt1); atomicAdd(&lcnt[2], cnt2);
  }
  __syncthreads();
  for (int idx = t; idx < KCL * DIM; idx += 256) atomicAdd(&ws[WS_SUMS + IT * SUMS_STRIDE + idx], lsum[idx]);
  if (t < KCL) atomicAdd(&ws[WS_SUMS + IT * SUMS_STRIDE + 3 * DIM + t], lcnt[t]);
}

// ================= k_main: fused cls MFMA + proto distances + epilogue =================
__global__ __launch_bounds__(256) void k_main(const float* __restrict__ zc,
                                              const float* __restrict__ zp,
                                              const float* __restrict__ b1,
                                              const float* __restrict__ W2,
                                              const float* __restrict__ b2,
                                              const int* __restrict__ pos_idx,
                                              const float* __restrict__ ws,
                                              float* __restrict__ out) {
  __shared__ float pp[KCL * DIM];          // shifted pos protos
  __shared__ float np[DIM];                // shifted neg proto
  __shared__ float pn[KCL + 1];            // proto norms, [3] = neg norm
  __shared__ __hip_bfloat16 Bs[HID][40];   // W1 staging, padded
  __shared__ float clsv[64];
  __shared__ float outst[64 * 4 + 192];    // lg | prob | o2 | assign | e(3*64)

  int t = threadIdx.x, w = t >> 6, l = t & 63;
  int i0 = blockIdx.x * 64;

  // ---- prologue: final center chain (4 iters) + shift; neg proto; norms ----
  for (int idx = t; idx < KCL * DIM; idx += 256) {
    int k = idx >> 9, d = idx & 511;
    int sel = (k == 0) ? 0 : ((k == 1) ? 4095 : 8191);
    float v = zp[(size_t)pos_idx[sel] * DIM + d];
#pragma unroll
    for (int j = 0; j < 4; ++j) {
      float cntv = ws[WS_SUMS + j * SUMS_STRIDE + 3 * DIM + k];
      float sv   = ws[WS_SUMS + j * SUMS_STRIDE + idx];
      v = (cntv > 0.f) ? sv / cntv : v;
    }
    pp[idx] = v + ws[WS_SHIFT_POS + d];
  }
  for (int d = t; d < DIM; d += 256)
    np[d] = ws[WS_NEGSUM + d] * (1.f / NNEGI) + ws[WS_SHIFT_NEG + d];
  __syncthreads();
  {
    float s = 0.f;
    if (w < KCL) {
#pragma unroll
      for (int m = 0; m < 8; ++m) { float v = pp[w * DIM + l + m * 64]; s += v * v; }
    } else {
#pragma unroll
      for (int m = 0; m < 8; ++m) { float v = np[l + m * 64]; s += v * v; }
    }
#pragma unroll
    for (int m = 1; m < 64; m <<= 1) s += __shfl_xor(s, m);
    if (l == 0) pn[w] = s;
  }
  if (blockIdx.x == 0) {
    for (int idx = t; idx < KCL * DIM; idx += 256) out[7 * NPTS + idx] = pp[idx];
    for (int d = t; d < DIM; d += 256)            out[7 * NPTS + KCL * DIM + d] = np[d];
  }

  // ---- cls phase: relu(z@W1^T + b1) @ W2^T + b2 via MFMA ----
  const __hip_bfloat16* W1bf = (const __hip_bfloat16*)(ws + WS_W1BF);
  f32x4 acc[8];
#pragma unroll
  for (int n = 0; n < 8; ++n) acc[n] = (f32x4){0.f, 0.f, 0.f, 0.f};
  int arow = i0 + w * 16 + (l & 15);
  const float* aptr = zc + (size_t)arow * DIM + (l >> 4) * 8;
  int srow = t >> 1, scol = (t & 1) * 16;

  for (int kc = 0; kc < DIM; kc += 32) {
    __syncthreads();
    {
      const float4* src = (const float4*)(W1bf + (size_t)srow * DIM + kc + scol);
      float4 v0 = src[0], v1 = src[1];
      *(float4*)(&Bs[srow][scol])     = v0;
      *(float4*)(&Bs[srow][scol + 8]) = v1;
    }
    __syncthreads();
    float4 a0 = *(const float4*)(aptr + kc);
    float4 a1 = *(const float4*)(aptr + kc + 4);
    bf16x8 af;
    af[0] = f2bf(a0.x); af[1] = f2bf(a0.y); af[2] = f2bf(a0.z); af[3] = f2bf(a0.w);
    af[4] = f2bf(a1.x); af[5] = f2bf(a1.y); af[6] = f2bf(a1.z); af[7] = f2bf(a1.w);
#pragma unroll
    for (int n = 0; n < 8; ++n) {
      bf16x8 bf = *(const bf16x8*)(&Bs[n * 16 + (l & 15)][(l >> 4) * 8]);
      acc[n] = __builtin_amdgcn_mfma_f32_16x16x32_bf16(af, bf, acc[n], 0, 0, 0);
    }
  }
  {
    float p[4] = {0.f, 0.f, 0.f, 0.f};
    int col_l = l & 15;
#pragma unroll
    for (int n = 0; n < 8; ++n) {
      int col = n * 16 + col_l;
      float bb = b1[col], w2 = W2[col];
#pragma unroll
      for (int r = 0; r < 4; ++r) {
        float h = acc[n][r] + bb;
        h = h > 0.f ? h : 0.f;
        p[r] += h * w2;
      }
    }
#pragma unroll
    for (int m = 1; m < 16; m <<= 1) {
#pragma unroll
      for (int r = 0; r < 4; ++r) p[r] += __shfl_xor(p[r], m);
    }
    if (col_l == 0) {
      float bias2 = b2[0];
      int rl = w * 16 + (l >> 4) * 4;
#pragma unroll
      for (int r = 0; r < 4; ++r) clsv[rl + r] = p[r] + bias2;
    }
  }
  __syncthreads();

  // ---- proto phase: distances + fused epilogue for the same 64 rows ----
  float ppr0[8], ppr1[8], ppr2[8], npr[8];
#pragma unroll
  for (int j = 0; j < 8; ++j) {
    ppr0[j] = pp[0 * DIM + l * 8 + j];
    ppr1[j] = pp[1 * DIM + l * 8 + j];
    ppr2[j] = pp[2 * DIM + l * 8 + j];
    npr[j]  = np[l * 8 + j];
  }
  float pn0 = pn[0], pn1 = pn[1], pn2 = pn[2], nn = pn[3];

  for (int r = 0; r < 16; ++r) {
    int rl = w * 16 + r;
    int i = i0 + rl;
    const float* xr = zp + (size_t)i * DIM + l * 8;
    float4 x0 = *(const float4*)(xr);
    float4 x1 = *(const float4*)(xr + 4);
    float x[8] = {x0.x, x0.y, x0.z, x0.w, x1.x, x1.y, x1.z, x1.w};
    float sx = 0.f, d0 = 0.f, d1 = 0.f, d2 = 0.f, dn = 0.f;
#pragma unroll
    for (int j = 0; j < 8; ++j) {
      sx += x[j] * x[j];
      d0 += x[j] * ppr0[j];
      d1 += x[j] * ppr1[j];
      d2 += x[j] * ppr2[j];
      dn += x[j] * npr[j];
    }
#pragma unroll
    for (int m = 1; m < 64; m <<= 1) {
      sx += __shfl_xor(sx, m);
      d0 += __shfl_xor(d0, m);
      d1 += __shfl_xor(d1, m);
      d2 += __shfl_xor(d2, m);
      dn += __shfl_xor(dn, m);
    }
    if (l == 0) {
      float e0 = sx + pn0 - 2.f * d0; e0 = e0 > 0.f ? e0 : 0.f;
      float e1 = sx + pn1 - 2.f * d1; e1 = e1 > 0.f ? e1 : 0.f;
      float e2 = sx + pn2 - 2.f * d2; e2 = e2 > 0.f ? e2 : 0.f;
      float dpos = e0; int a = 0;
      if (e1 < dpos) { dpos = e1; a = 1; }
      if (e2 < dpos) { dpos = e2; a = 2; }
      float dneg = (sx + nn - 2.f * dn) * (1.f / DIM);
      float plog = (dneg - dpos) * 0.04419417382415922f;  // 1/sqrt(512)
      float o2 = 0.2f * plog;
      float lg = (clsv[rl] + o2) * 0.4f;                  // /2.5
      float prob = 1.f / (1.f + expf(-lg));
      outst[rl]       = lg;
      outst[64 + rl]  = prob;
      outst[128 + rl] = o2;
      outst[192 + rl] = (float)a;
      outst[256 + 3 * rl]     = e0;
      outst[256 + 3 * rl + 1] = e1;
      outst[256 + 3 * rl + 2] = e2;
    }
  }
  __syncthreads();
  if (t < 64) {
    out[i0 + t]            = outst[t];
    out[NPTS + i0 + t]     = outst[64 + t];
    out[2 * NPTS + i0 + t] = outst[128 + t];
    out[3 * NPTS + i0 + t] = outst[192 + t];
  } else {
    int u = t - 64;
    if (u < 192) out[4 * NPTS + 3 * i0 + u] = outst[256 + u];
  }
}

extern "C" void kernel_launch(void* const* d_in, const int* in_sizes, int n_in,
                              void* d_out, int out_size, void* d_ws, size_t ws_size,
                              hipStream_t stream) {
  const float* z_cls   = (const float*)d_in[0];
  const float* z_proto = (const float*)d_in[1];
  const float* pos_ctx = (const float*)d_in[2];
  const float* neg_ctx = (const float*)d_in[3];
  const float* W1      = (const float*)d_in[4];
  const float* b1      = (const float*)d_in[5];
  const float* W2      = (const float*)d_in[6];
  const float* b2      = (const float*)d_in[7];
  const float* Wp      = (const float*)d_in[8];
  const float* bp      = (const float*)d_in[9];
  const float* Wn      = (const float*)d_in[10];
  const float* bn      = (const float*)d_in[11];
  const int* pos_idx   = (const int*)d_in[12];
  const int* neg_idx   = (const int*)d_in[13];
  float* out           = (float*)d_out;
  float* ws            = (float*)d_ws;

  k_prep<<<417, 256, 0, stream>>>(W1, Wp, bp, Wn, bn, pos_ctx, neg_ctx, z_proto, neg_idx, ws);
  k_km<0><<<129, 256, 0, stream>>>(z_proto, pos_idx, ws);
  k_km<1><<<128, 256, 0, stream>>>(z_proto, pos_idx, ws);
  k_km<2><<<128, 256, 0, stream>>>(z_proto, pos_idx, ws);
  k_km<3><<<128, 256, 0, stream>>>(z_proto, pos_idx, ws);
  k_main<<<NPTS / 64, 256, 0, stream>>>(z_cls, z_proto, b1, W2, b2, pos_idx, ws, out);
}

// Round 4
// 289.910 us; speedup vs baseline: 1.0677x; 1.0163x over previous
//
#include <hip/hip_runtime.h>
#include <hip/hip_bf16.h>

#define NPTS 131072
#define DIM  512
#define HID  128
#define KCL  3
#define NPOSI 8192
#define NNEGI 8192

typedef __attribute__((ext_vector_type(8))) short bf16x8;
typedef __attribute__((ext_vector_type(4))) float f32x4;

// ws layout (float offsets)
enum {
  WS_SHIFT_POS = 0,       // 512
  WS_SHIFT_NEG = 512,     // 512
  WS_NEGSUM    = 1024,    // 512
  WS_NEGPART   = 1536,    // 128*512 -> ends 67072
  WS_SUMS      = 67072,   // 4 iters * 1539 -> ends 73228
  WS_W1FRAG    = 73232,   // 8192 fragments * 16B = 32768 floats -> ends 106000 (~424KB)
};
#define SUMS_STRIDE 1539

__device__ __forceinline__ short f2bf(float x) {
  __hip_bfloat16 h = __float2bfloat16(x);
  return *reinterpret_cast<short*>(&h);
}

// ================= k_prep: W1 frag-swizzle | calib | negmean partials | zero sums =================
// W1 fragment layout: frag[(kc*8+n)*64 + lane] = bf16x8 of W1[n*16+(lane&15)][kc*32+(lane>>4)*8 .. +8]
__global__ __launch_bounds__(256) void k_prep(const float* __restrict__ W1,
                                              const float* __restrict__ Wp, const float* __restrict__ bp,
                                              const float* __restrict__ Wn, const float* __restrict__ bn,
                                              const float* __restrict__ pos_ctx, const float* __restrict__ neg_ctx,
                                              const float* __restrict__ zp, const int* __restrict__ neg_idx,
                                              float* __restrict__ ws) {
  int bid = blockIdx.x, t = threadIdx.x;
  if (bid < 32) {
    // pre-swizzled W1 MFMA fragments (bf16)
    int fid = bid * 256 + t;           // 0..8191
    int kc = fid >> 9;
    int n  = (fid >> 6) & 7;
    int l  = fid & 63;
    int row = n * 16 + (l & 15);
    int col = kc * 32 + (l >> 4) * 8;
    const float* src = W1 + (size_t)row * DIM + col;
    float4 v0 = *(const float4*)(src);
    float4 v1 = *(const float4*)(src + 4);
    bf16x8 f;
    f[0] = f2bf(v0.x); f[1] = f2bf(v0.y); f[2] = f2bf(v0.z); f[3] = f2bf(v0.w);
    f[4] = f2bf(v1.x); f[5] = f2bf(v1.y); f[6] = f2bf(v1.z); f[7] = f2bf(v1.w);
    ((bf16x8*)(ws + WS_W1FRAG))[fid] = f;
  } else if (bid < 64) {
    // calibration matvec: shift = 0.15*(W @ ctx + b)
    int b = bid - 32;                  // 0..31
    int mat = b >> 4;
    const float* W    = mat ? Wn : Wp;
    const float* bias = mat ? bn : bp;
    const float* ctx  = mat ? neg_ctx : pos_ctx;
    float* outp = ws + (mat ? WS_SHIFT_NEG : WS_SHIFT_POS);
    int row = (b & 15) * 32 + (t >> 3);
    int sub = t & 7;
    const float* wr = W + row * DIM + sub * 64;
    const float* cr = ctx + sub * 64;
    float s = 0.f;
#pragma unroll
    for (int j = 0; j < 64; j += 4) {
      float4 w4 = *(const float4*)(wr + j);
      float4 c4 = *(const float4*)(cr + j);
      s += w4.x * c4.x + w4.y * c4.y + w4.z * c4.z + w4.w * c4.w;
    }
    s += __shfl_xor(s, 1);
    s += __shfl_xor(s, 2);
    s += __shfl_xor(s, 4);
    if (sub == 0) outp[row] = 0.15f * (s + bias[row]);
  } else if (bid < 192) {
    // neg gather-mean partials
    int j = bid - 64;                  // 0..127
    int c0 = t * 2;
    float a0 = 0.f, a1 = 0.f;
    int j0 = j * 64;
    for (int jj = 0; jj < 64; ++jj) {
      int row = neg_idx[j0 + jj];
      float2 v = *(const float2*)(zp + (size_t)row * DIM + c0);
      a0 += v.x; a1 += v.y;
    }
    ws[WS_NEGPART + j * DIM + c0]     = a0;
    ws[WS_NEGPART + j * DIM + c0 + 1] = a1;
  } else {
    for (int idx = t; idx < 4 * SUMS_STRIDE; idx += 256) ws[WS_SUMS + idx] = 0.f;
  }
}

// ================= k_km<IT>: recompute center chain, assign, accumulate =================
template <int IT>
__global__ __launch_bounds__(256) void k_km(const float* __restrict__ zp,
                                            const int* __restrict__ pos_idx,
                                            float* __restrict__ ws) {
  int bid = blockIdx.x, t = threadIdx.x;
  if (IT == 0 && bid == 256) {
    // reduce negmean partials -> NEGSUM
    int c0 = t * 2;
    float a0 = 0.f, a1 = 0.f;
#pragma unroll 8
    for (int j = 0; j < 128; ++j) {
      float2 v = *(const float2*)(ws + WS_NEGPART + j * DIM + c0);
      a0 += v.x; a1 += v.y;
    }
    ws[WS_NEGSUM + c0]     = a0;
    ws[WS_NEGSUM + c0 + 1] = a1;
    return;
  }
  __shared__ float cc[KCL * DIM];
  __shared__ float cn[KCL];
  __shared__ float lsum[KCL * DIM];
  __shared__ float lcnt[KCL];
  int w = t >> 6, l = t & 63;

  for (int idx = t; idx < KCL * DIM; idx += 256) lsum[idx] = 0.f;
  if (t < KCL) lcnt[t] = 0.f;

  for (int idx = t; idx < KCL * DIM; idx += 256) {
    int k = idx >> 9;
    int sel = (k == 0) ? 0 : ((k == 1) ? 4095 : 8191);
    float v = zp[(size_t)pos_idx[sel] * DIM + (idx & 511)];
#pragma unroll
    for (int j = 0; j < IT; ++j) {
      float cntv = ws[WS_SUMS + j * SUMS_STRIDE + 3 * DIM + k];
      float sv   = ws[WS_SUMS + j * SUMS_STRIDE + idx];
      v = (cntv > 0.f) ? sv / cntv : v;
    }
    cc[idx] = v;
  }
  __syncthreads();
  if (w < KCL) {
    float s = 0.f;
#pragma unroll
    for (int m = 0; m < 8; ++m) { float v = cc[w * DIM + l + m * 64]; s += v * v; }
#pragma unroll
    for (int m = 1; m < 64; m <<= 1) s += __shfl_xor(s, m);
    if (l == 0) cn[w] = s;
  }
  __syncthreads();

  float ck0[8], ck1[8], ck2[8];
#pragma unroll
  for (int j = 0; j < 8; ++j) {
    ck0[j] = cc[0 * DIM + l * 8 + j];
    ck1[j] = cc[1 * DIM + l * 8 + j];
    ck2[j] = cc[2 * DIM + l * 8 + j];
  }
  float cn0 = cn[0], cn1 = cn[1], cn2 = cn[2];
  float acc0[8] = {0,0,0,0,0,0,0,0}, acc1[8] = {0,0,0,0,0,0,0,0}, acc2[8] = {0,0,0,0,0,0,0,0};
  float cnt0 = 0.f, cnt1 = 0.f, cnt2 = 0.f;

  int wid = bid * 4 + w;   // 1024 waves, 8 rows each
  for (int p = wid; p < NPOSI; p += 1024) {
    int row = pos_idx[p];
    const float* xr = zp + (size_t)row * DIM + l * 8;
    float4 x0 = *(const float4*)(xr);
    float4 x1 = *(const float4*)(xr + 4);
    float x[8] = {x0.x, x0.y, x0.z, x0.w, x1.x, x1.y, x1.z, x1.w};
    float d0 = 0.f, d1 = 0.f, d2 = 0.f;
#pragma unroll
    for (int j = 0; j < 8; ++j) { d0 += x[j] * ck0[j]; d1 += x[j] * ck1[j]; d2 += x[j] * ck2[j]; }
#pragma unroll
    for (int m = 1; m < 64; m <<= 1) {
      d0 += __shfl_xor(d0, m); d1 += __shfl_xor(d1, m); d2 += __shfl_xor(d2, m);
    }
    float t0 = cn0 - 2.f * d0, t1 = cn1 - 2.f * d1, t2 = cn2 - 2.f * d2;
    int a = 0; float best = t0;
    if (t1 < best) { best = t1; a = 1; }
    if (t2 < best) { best = t2; a = 2; }
    if (a == 0)      { cnt0 += 1.f;
#pragma unroll
      for (int j = 0; j < 8; ++j) acc0[j] += x[j]; }
    else if (a == 1) { cnt1 += 1.f;
#pragma unroll
      for (int j = 0; j < 8; ++j) acc1[j] += x[j]; }
    else             { cnt2 += 1.f;
#pragma unroll
      for (int j = 0; j < 8; ++j) acc2[j] += x[j]; }
  }
#pragma unroll
  for (int j = 0; j < 8; ++j) {
    atomicAdd(&lsum[0 * DIM + l * 8 + j], acc0[j]);
    atomicAdd(&lsum[1 * DIM + l * 8 + j], acc1[j]);
    atomicAdd(&lsum[2 * DIM + l * 8 + j], acc2[j]);
  }
  if (l == 0) {
    atomicAdd(&lcnt[0], cnt0); atomicAdd(&lcnt[1], cnt1); atomicAdd(&lcnt[2], cnt2);
  }
  __syncthreads();
  for (int idx = t; idx < KCL * DIM; idx += 256) atomicAdd(&ws[WS_SUMS + IT * SUMS_STRIDE + idx], lsum[idx]);
  if (t < KCL) atomicAdd(&ws[WS_SUMS + IT * SUMS_STRIDE + 3 * DIM + t], lcnt[t]);
}

// ================= k_main: barrier-free MFMA K-loop (cls + proto distances) =================
__global__ __launch_bounds__(256) void k_main(const float* __restrict__ zc,
                                              const float* __restrict__ zp,
                                              const float* __restrict__ b1,
                                              const float* __restrict__ W2,
                                              const float* __restrict__ b2,
                                              const int* __restrict__ pos_idx,
                                              const float* __restrict__ ws,
                                              float* __restrict__ out) {
  __shared__ float pp[KCL * DIM];
  __shared__ float np[DIM];
  __shared__ float pn[4];
  __shared__ float clsv[64];
  __shared__ float sxs[64];
  __shared__ float dstg[4][64];
  __shared__ float outst[448];
  __shared__ bf16x8 pfrag[1024];     // 16 kc * 64 lanes, 16KB

  int t = threadIdx.x, w = t >> 6, l = t & 63;
  int i0 = blockIdx.x * 64;

  // ---- prologue: center chain + shifts; neg proto ----
  for (int idx = t; idx < KCL * DIM; idx += 256) {
    int k = idx >> 9, d = idx & 511;
    int sel = (k == 0) ? 0 : ((k == 1) ? 4095 : 8191);
    float v = zp[(size_t)pos_idx[sel] * DIM + d];
#pragma unroll
    for (int j = 0; j < 4; ++j) {
      float cntv = ws[WS_SUMS + j * SUMS_STRIDE + 3 * DIM + k];
      float sv   = ws[WS_SUMS + j * SUMS_STRIDE + idx];
      v = (cntv > 0.f) ? sv / cntv : v;
    }
    pp[idx] = v + ws[WS_SHIFT_POS + d];
  }
  for (int d = t; d < DIM; d += 256)
    np[d] = ws[WS_NEGSUM + d] * (1.f / NNEGI) + ws[WS_SHIFT_NEG + d];
  __syncthreads();
  // norms (wave w: protos 0..2, neg = 3)
  {
    float s = 0.f;
    const float* src = (w < 3) ? (pp + w * DIM) : np;
#pragma unroll
    for (int m = 0; m < 8; ++m) { float v = src[l + m * 64]; s += v * v; }
#pragma unroll
    for (int m = 1; m < 64; m <<= 1) s += __shfl_xor(s, m);
    if (l == 0) pn[w] = s;
  }
  // proto B-fragments: cols 0..2 = pos protos, 3 = neg, 4..15 = zero
  for (int idx = t; idx < 1024; idx += 256) {
    int kc = idx >> 6, ll = idx & 63, c = ll & 15, ko = (ll >> 4) * 8;
    bf16x8 v;
#pragma unroll
    for (int j = 0; j < 8; ++j) {
      float f = (c < 3) ? pp[c * DIM + kc * 32 + ko + j]
                        : ((c == 3) ? np[kc * 32 + ko + j] : 0.f);
      v[j] = f2bf(f);
    }
    pfrag[idx] = v;
  }
  if (blockIdx.x == 0) {
    for (int idx = t; idx < KCL * DIM; idx += 256) out[7 * NPTS + idx] = pp[idx];
    for (int d = t; d < DIM; d += 256)            out[7 * NPTS + KCL * DIM + d] = np[d];
  }
  __syncthreads();

  // ---- K-loop: no barriers; W1 fragments from L2-hot pre-swizzled ws ----
  const bf16x8* w1f = (const bf16x8*)(ws + WS_W1FRAG);
  int arow = i0 + w * 16 + (l & 15);
  const float* zcrow = zc + (size_t)arow * DIM + (l >> 4) * 8;
  const float* zprow = zp + (size_t)arow * DIM + (l >> 4) * 8;

  f32x4 accc[8];
#pragma unroll
  for (int n = 0; n < 8; ++n) accc[n] = (f32x4){0.f, 0.f, 0.f, 0.f};
  f32x4 accd = (f32x4){0.f, 0.f, 0.f, 0.f};
  float sx = 0.f;

  for (int kc = 0; kc < 16; ++kc) {
    float4 c0 = *(const float4*)(zcrow + kc * 32);
    float4 c1 = *(const float4*)(zcrow + kc * 32 + 4);
    float4 p0 = *(const float4*)(zprow + kc * 32);
    float4 p1 = *(const float4*)(zprow + kc * 32 + 4);
    bf16x8 af, ap;
    af[0] = f2bf(c0.x); af[1] = f2bf(c0.y); af[2] = f2bf(c0.z); af[3] = f2bf(c0.w);
    af[4] = f2bf(c1.x); af[5] = f2bf(c1.y); af[6] = f2bf(c1.z); af[7] = f2bf(c1.w);
    ap[0] = f2bf(p0.x); ap[1] = f2bf(p0.y); ap[2] = f2bf(p0.z); ap[3] = f2bf(p0.w);
    ap[4] = f2bf(p1.x); ap[5] = f2bf(p1.y); ap[6] = f2bf(p1.z); ap[7] = f2bf(p1.w);
    sx += p0.x * p0.x + p0.y * p0.y + p0.z * p0.z + p0.w * p0.w
        + p1.x * p1.x + p1.y * p1.y + p1.z * p1.z + p1.w * p1.w;
    accd = __builtin_amdgcn_mfma_f32_16x16x32_bf16(ap, pfrag[kc * 64 + l], accd, 0, 0, 0);
    const bf16x8* wrow = w1f + kc * 512 + l;
#pragma unroll
    for (int n = 0; n < 8; ++n)
      accc[n] = __builtin_amdgcn_mfma_f32_16x16x32_bf16(af, wrow[n * 64], accc[n], 0, 0, 0);
  }

  // ---- epilogue assembly ----
  sx += __shfl_xor(sx, 16);
  sx += __shfl_xor(sx, 32);          // lane l: full ||x||^2 of row (l&15)
  if (l < 16) sxs[w * 16 + l] = sx;

  {
    float pcl[4] = {0.f, 0.f, 0.f, 0.f};
    int col_l = l & 15;
#pragma unroll
    for (int n = 0; n < 8; ++n) {
      int col = n * 16 + col_l;
      float bb = b1[col], w2v = W2[col];
#pragma unroll
      for (int r = 0; r < 4; ++r) {
        float h = accc[n][r] + bb;
        h = h > 0.f ? h : 0.f;
        pcl[r] += h * w2v;
      }
    }
#pragma unroll
    for (int m = 1; m < 16; m <<= 1) {
#pragma unroll
      for (int r = 0; r < 4; ++r) pcl[r] += __shfl_xor(pcl[r], m);
    }
    if (col_l == 0) {
      float b2v = b2[0];
#pragma unroll
      for (int r = 0; r < 4; ++r) clsv[w * 16 + (l >> 4) * 4 + r] = pcl[r] + b2v;
    }
  }
  {
    int c = l & 15;
    if (c < 4) {
#pragma unroll
      for (int j = 0; j < 4; ++j) dstg[c][w * 16 + (l >> 4) * 4 + j] = accd[j];
    }
  }
  __syncthreads();

  if (t < 64) {
    float sxv = sxs[t];
    float d0 = dstg[0][t], d1 = dstg[1][t], d2 = dstg[2][t], dn = dstg[3][t];
    float e0 = sxv + pn[0] - 2.f * d0; e0 = fmaxf(e0, 0.f);
    float e1 = sxv + pn[1] - 2.f * d1; e1 = fmaxf(e1, 0.f);
    float e2 = sxv + pn[2] - 2.f * d2; e2 = fmaxf(e2, 0.f);
    float dpos = e0; int a = 0;
    if (e1 < dpos) { dpos = e1; a = 1; }
    if (e2 < dpos) { dpos = e2; a = 2; }
    float dneg = (sxv + pn[3] - 2.f * dn) * (1.f / DIM);
    float plog = (dneg - dpos) * 0.04419417382415922f;   // 1/sqrt(512)
    float o2 = 0.2f * plog;
    float lg = (clsv[t] + o2) * 0.4f;                    // /2.5
    float prob = 1.f / (1.f + expf(-lg));
    outst[t]        = lg;
    outst[64 + t]   = prob;
    outst[128 + t]  = o2;
    outst[192 + t]  = (float)a;
    outst[256 + 3 * t]     = e0;
    outst[256 + 3 * t + 1] = e1;
    outst[256 + 3 * t + 2] = e2;
  }
  __syncthreads();
  if (t < 64) {
    out[i0 + t]            = outst[t];
    out[NPTS + i0 + t]     = outst[64 + t];
    out[2 * NPTS + i0 + t] = outst[128 + t];
    out[3 * NPTS + i0 + t] = outst[192 + t];
  } else {
    int u = t - 64;
    if (u < 192) out[4 * NPTS + 3 * i0 + u] = outst[256 + u];
  }
}

extern "C" void kernel_launch(void* const* d_in, const int* in_sizes, int n_in,
                              void* d_out, int out_size, void* d_ws, size_t ws_size,
                              hipStream_t stream) {
  const float* z_cls   = (const float*)d_in[0];
  const float* z_proto = (const float*)d_in[1];
  const float* pos_ctx = (const float*)d_in[2];
  const float* neg_ctx = (const float*)d_in[3];
  const float* W1      = (const float*)d_in[4];
  const float* b1      = (const float*)d_in[5];
  const float* W2      = (const float*)d_in[6];
  const float* b2      = (const float*)d_in[7];
  const float* Wp      = (const float*)d_in[8];
  const float* bp      = (const float*)d_in[9];
  const float* Wn      = (const float*)d_in[10];
  const float* bn      = (const float*)d_in[11];
  const int* pos_idx   = (const int*)d_in[12];
  const int* neg_idx   = (const int*)d_in[13];
  float* out           = (float*)d_out;
  float* ws            = (float*)d_ws;

  k_prep<<<193, 256, 0, stream>>>(W1, Wp, bp, Wn, bn, pos_ctx, neg_ctx, z_proto, neg_idx, ws);
  k_km<0><<<257, 256, 0, stream>>>(z_proto, pos_idx, ws);
  k_km<1><<<256, 256, 0, stream>>>(z_proto, pos_idx, ws);
  k_km<2><<<256, 256, 0, stream>>>(z_proto, pos_idx, ws);
  k_km<3><<<256, 256, 0, stream>>>(z_proto, pos_idx, ws);
  k_main<<<NPTS / 64, 256, 0, stream>>>(z_cls, z_proto, b1, W2, b2, pos_idx, ws, out);
}

// Round 5
// 276.136 us; speedup vs baseline: 1.1209x; 1.0499x over previous
//
#include <hip/hip_runtime.h>
#include <hip/hip_bf16.h>

#define NPTS 131072
#define DIM  512
#define HID  128
#define KCL  3
#define NPOSI 8192
#define NNEGI 8192

typedef __attribute__((ext_vector_type(8))) short bf16x8;
typedef __attribute__((ext_vector_type(4))) float f32x4;

// ws layout (float offsets)
enum {
  WS_SHIFT_POS = 0,        // 512
  WS_SHIFT_NEG = 512,      // 512
  WS_NEGSUM    = 1024,     // 512
  WS_NEGPART   = 1536,     // 256*512 -> ends 132608
  WS_SUMS      = 132608,   // 4*1539 -> ends 138764
  WS_PPROTO    = 138764,   // 4*512 ([0..2] pos, [3] neg) -> 140812
  WS_PN        = 140812,   // 4 -> 140816
  WS_W1FRAG    = 140816,   // 8192 frags * 4 floats = 32768 -> 173584
  WS_CLSL      = 173584,   // 131072 -> 304656 floats (~1.22 MB)
};
#define SUMS_STRIDE 1539

__device__ __forceinline__ short f2bf(float x) {
  __hip_bfloat16 h = __float2bfloat16(x);
  return *reinterpret_cast<short*>(&h);
}

// ================= k_prep: W1 frag-swizzle | calib | negmean partials | zero sums =================
__global__ __launch_bounds__(256) void k_prep(const float* __restrict__ W1,
                                              const float* __restrict__ Wp, const float* __restrict__ bp,
                                              const float* __restrict__ Wn, const float* __restrict__ bn,
                                              const float* __restrict__ pos_ctx, const float* __restrict__ neg_ctx,
                                              const float* __restrict__ zp, const int* __restrict__ neg_idx,
                                              float* __restrict__ ws) {
  int bid = blockIdx.x, t = threadIdx.x;
  if (bid < 32) {
    // pre-swizzled W1 MFMA fragments (bf16)
    int fid = bid * 256 + t;           // 0..8191
    int kc = fid >> 9;
    int n  = (fid >> 6) & 7;
    int l  = fid & 63;
    int row = n * 16 + (l & 15);
    int col = kc * 32 + (l >> 4) * 8;
    const float* src = W1 + (size_t)row * DIM + col;
    float4 v0 = *(const float4*)(src);
    float4 v1 = *(const float4*)(src + 4);
    bf16x8 f;
    f[0] = f2bf(v0.x); f[1] = f2bf(v0.y); f[2] = f2bf(v0.z); f[3] = f2bf(v0.w);
    f[4] = f2bf(v1.x); f[5] = f2bf(v1.y); f[6] = f2bf(v1.z); f[7] = f2bf(v1.w);
    ((bf16x8*)(ws + WS_W1FRAG))[fid] = f;
  } else if (bid < 64) {
    // calibration matvec: shift = 0.15*(W @ ctx + b)
    int b = bid - 32;
    int mat = b >> 4;
    const float* W    = mat ? Wn : Wp;
    const float* bias = mat ? bn : bp;
    const float* ctx  = mat ? neg_ctx : pos_ctx;
    float* outp = ws + (mat ? WS_SHIFT_NEG : WS_SHIFT_POS);
    int row = (b & 15) * 32 + (t >> 3);
    int sub = t & 7;
    const float* wr = W + row * DIM + sub * 64;
    const float* cr = ctx + sub * 64;
    float s = 0.f;
#pragma unroll
    for (int j = 0; j < 64; j += 4) {
      float4 w4 = *(const float4*)(wr + j);
      float4 c4 = *(const float4*)(cr + j);
      s += w4.x * c4.x + w4.y * c4.y + w4.z * c4.z + w4.w * c4.w;
    }
    s += __shfl_xor(s, 1);
    s += __shfl_xor(s, 2);
    s += __shfl_xor(s, 4);
    if (sub == 0) outp[row] = 0.15f * (s + bias[row]);
  } else if (bid < 320) {
    // neg gather-mean partials: 256 blocks x 32 rows, 4-deep pipelined gathers
    int jb = bid - 64;
    int c0 = t * 2;
    float a0 = 0.f, a1 = 0.f;
    int base = jb * 32;
#pragma unroll 4
    for (int jj = 0; jj < 32; ++jj) {
      int row = neg_idx[base + jj];
      float2 v = *(const float2*)(zp + (size_t)row * DIM + c0);
      a0 += v.x; a1 += v.y;
    }
    ws[WS_NEGPART + jb * DIM + c0]     = a0;
    ws[WS_NEGPART + jb * DIM + c0 + 1] = a1;
  } else {
    for (int idx = t; idx < 4 * SUMS_STRIDE; idx += 256) ws[WS_SUMS + idx] = 0.f;
  }
}

// ================= k_km<IT>: recompute center chain, assign, accumulate =================
template <int IT>
__global__ __launch_bounds__(256) void k_km(const float* __restrict__ zp,
                                            const int* __restrict__ pos_idx,
                                            float* __restrict__ ws) {
  int bid = blockIdx.x, t = threadIdx.x;
  if (IT == 0 && bid == 256) {
    int c0 = t * 2;
    float a0 = 0.f, a1 = 0.f;
#pragma unroll 8
    for (int j = 0; j < 256; ++j) {
      float2 v = *(const float2*)(ws + WS_NEGPART + j * DIM + c0);
      a0 += v.x; a1 += v.y;
    }
    ws[WS_NEGSUM + c0]     = a0;
    ws[WS_NEGSUM + c0 + 1] = a1;
    return;
  }
  __shared__ float cc[KCL * DIM];
  __shared__ float cn[KCL];
  __shared__ float lsum[KCL * DIM];
  __shared__ float lcnt[KCL];
  int w = t >> 6, l = t & 63;

  for (int idx = t; idx < KCL * DIM; idx += 256) lsum[idx] = 0.f;
  if (t < KCL) lcnt[t] = 0.f;

  for (int idx = t; idx < KCL * DIM; idx += 256) {
    int k = idx >> 9;
    int sel = (k == 0) ? 0 : ((k == 1) ? 4095 : 8191);
    float v = zp[(size_t)pos_idx[sel] * DIM + (idx & 511)];
#pragma unroll
    for (int j = 0; j < IT; ++j) {
      float cntv = ws[WS_SUMS + j * SUMS_STRIDE + 3 * DIM + k];
      float sv   = ws[WS_SUMS + j * SUMS_STRIDE + idx];
      v = (cntv > 0.f) ? sv / cntv : v;
    }
    cc[idx] = v;
  }
  __syncthreads();
  if (w < KCL) {
    float s = 0.f;
#pragma unroll
    for (int m = 0; m < 8; ++m) { float v = cc[w * DIM + l + m * 64]; s += v * v; }
#pragma unroll
    for (int m = 1; m < 64; m <<= 1) s += __shfl_xor(s, m);
    if (l == 0) cn[w] = s;
  }
  __syncthreads();

  float ck0[8], ck1[8], ck2[8];
#pragma unroll
  for (int j = 0; j < 8; ++j) {
    ck0[j] = cc[0 * DIM + l * 8 + j];
    ck1[j] = cc[1 * DIM + l * 8 + j];
    ck2[j] = cc[2 * DIM + l * 8 + j];
  }
  float cn0 = cn[0], cn1 = cn[1], cn2 = cn[2];
  float acc0[8] = {0,0,0,0,0,0,0,0}, acc1[8] = {0,0,0,0,0,0,0,0}, acc2[8] = {0,0,0,0,0,0,0,0};
  float cnt0 = 0.f, cnt1 = 0.f, cnt2 = 0.f;

  int wid = bid * 4 + w;   // 1024 waves, 8 rows each
#pragma unroll 2
  for (int p = wid; p < NPOSI; p += 1024) {
    int row = pos_idx[p];
    const float* xr = zp + (size_t)row * DIM + l * 8;
    float4 x0 = *(const float4*)(xr);
    float4 x1 = *(const float4*)(xr + 4);
    float x[8] = {x0.x, x0.y, x0.z, x0.w, x1.x, x1.y, x1.z, x1.w};
    float d0 = 0.f, d1 = 0.f, d2 = 0.f;
#pragma unroll
    for (int j = 0; j < 8; ++j) { d0 += x[j] * ck0[j]; d1 += x[j] * ck1[j]; d2 += x[j] * ck2[j]; }
#pragma unroll
    for (int m = 1; m < 64; m <<= 1) {
      d0 += __shfl_xor(d0, m); d1 += __shfl_xor(d1, m); d2 += __shfl_xor(d2, m);
    }
    float t0 = cn0 - 2.f * d0, t1 = cn1 - 2.f * d1, t2 = cn2 - 2.f * d2;
    int a = 0; float best = t0;
    if (t1 < best) { best = t1; a = 1; }
    if (t2 < best) { best = t2; a = 2; }
    if (a == 0)      { cnt0 += 1.f;
#pragma unroll
      for (int j = 0; j < 8; ++j) acc0[j] += x[j]; }
    else if (a == 1) { cnt1 += 1.f;
#pragma unroll
      for (int j = 0; j < 8; ++j) acc1[j] += x[j]; }
    else             { cnt2 += 1.f;
#pragma unroll
      for (int j = 0; j < 8; ++j) acc2[j] += x[j]; }
  }
#pragma unroll
  for (int j = 0; j < 8; ++j) {
    atomicAdd(&lsum[0 * DIM + l * 8 + j], acc0[j]);
    atomicAdd(&lsum[1 * DIM + l * 8 + j], acc1[j]);
    atomicAdd(&lsum[2 * DIM + l * 8 + j], acc2[j]);
  }
  if (l == 0) {
    atomicAdd(&lcnt[0], cnt0); atomicAdd(&lcnt[1], cnt1); atomicAdd(&lcnt[2], cnt2);
  }
  __syncthreads();
  for (int idx = t; idx < KCL * DIM; idx += 256) atomicAdd(&ws[WS_SUMS + IT * SUMS_STRIDE + idx], lsum[idx]);
  if (t < KCL) atomicAdd(&ws[WS_SUMS + IT * SUMS_STRIDE + 3 * DIM + t], lcnt[t]);
}

// ================= k_fin: finalize prototypes + norms once =================
__global__ __launch_bounds__(256) void k_fin(const float* __restrict__ zp,
                                             const int* __restrict__ pos_idx,
                                             float* __restrict__ ws,
                                             float* __restrict__ out) {
  __shared__ __align__(16) float pp[4 * DIM];
  int t = threadIdx.x, w = t >> 6, l = t & 63;
  for (int idx = t; idx < KCL * DIM; idx += 256) {
    int k = idx >> 9, d = idx & 511;
    int sel = (k == 0) ? 0 : ((k == 1) ? 4095 : 8191);
    float v = zp[(size_t)pos_idx[sel] * DIM + d];
#pragma unroll
    for (int j = 0; j < 4; ++j) {
      float cntv = ws[WS_SUMS + j * SUMS_STRIDE + 3 * DIM + k];
      float sv   = ws[WS_SUMS + j * SUMS_STRIDE + idx];
      v = (cntv > 0.f) ? sv / cntv : v;
    }
    pp[idx] = v + ws[WS_SHIFT_POS + d];
  }
  for (int d = t; d < DIM; d += 256)
    pp[3 * DIM + d] = ws[WS_NEGSUM + d] * (1.f / NNEGI) + ws[WS_SHIFT_NEG + d];
  __syncthreads();
  {
    float s = 0.f;
#pragma unroll
    for (int m = 0; m < 8; ++m) { float v = pp[w * DIM + l + m * 64]; s += v * v; }
#pragma unroll
    for (int m = 1; m < 64; m <<= 1) s += __shfl_xor(s, m);
    if (l == 0) ws[WS_PN + w] = s;
  }
  for (int idx = t; idx < 4 * DIM; idx += 256) {
    ws[WS_PPROTO + idx] = pp[idx];
    out[7 * NPTS + idx] = pp[idx];
  }
}

// ================= k_cls: MFMA GEMM with explicit prefetch (A 3-deep HBM, B 1-deep L2) =================
__global__ __launch_bounds__(256, 2) void k_cls(const float* __restrict__ zc,
                                                const float* __restrict__ b1,
                                                const float* __restrict__ W2,
                                                const float* __restrict__ b2,
                                                float* __restrict__ ws) {
  int t = threadIdx.x, w = t >> 6, l = t & 63;
  int i0 = blockIdx.x * 64;
  const bf16x8* w1f = (const bf16x8*)(ws + WS_W1FRAG);
  int arow = i0 + w * 16 + (l & 15);
  const float* aptr = zc + (size_t)arow * DIM + (l >> 4) * 8;

  f32x4 acc[8];
#pragma unroll
  for (int n = 0; n < 8; ++n) acc[n] = (f32x4){0.f, 0.f, 0.f, 0.f};

  float4 A[3][2];
  bf16x8 B[2][8];
#pragma unroll
  for (int s = 0; s < 3; ++s) {
    A[s][0] = *(const float4*)(aptr + s * 32);
    A[s][1] = *(const float4*)(aptr + s * 32 + 4);
  }
#pragma unroll
  for (int n = 0; n < 8; ++n) B[0][n] = w1f[n * 64 + l];

#pragma unroll
  for (int kc = 0; kc < 16; ++kc) {
    float4 a0 = A[kc % 3][0], a1 = A[kc % 3][1];
    bf16x8 af;
    af[0] = f2bf(a0.x); af[1] = f2bf(a0.y); af[2] = f2bf(a0.z); af[3] = f2bf(a0.w);
    af[4] = f2bf(a1.x); af[5] = f2bf(a1.y); af[6] = f2bf(a1.z); af[7] = f2bf(a1.w);
    if (kc + 3 < 16) {
      A[kc % 3][0] = *(const float4*)(aptr + (kc + 3) * 32);
      A[kc % 3][1] = *(const float4*)(aptr + (kc + 3) * 32 + 4);
    }
    if (kc + 1 < 16) {
#pragma unroll
      for (int n = 0; n < 8; ++n) B[(kc + 1) & 1][n] = w1f[(kc + 1) * 512 + n * 64 + l];
    }
#pragma unroll
    for (int n = 0; n < 8; ++n)
      acc[n] = __builtin_amdgcn_mfma_f32_16x16x32_bf16(af, B[kc & 1][n], acc[n], 0, 0, 0);
  }

  // epilogue: relu + W2 dot -> cls_logit
  float p[4] = {0.f, 0.f, 0.f, 0.f};
  int col_l = l & 15;
#pragma unroll
  for (int n = 0; n < 8; ++n) {
    int col = n * 16 + col_l;
    float bb = b1[col], w2v = W2[col];
#pragma unroll
    for (int r = 0; r < 4; ++r) {
      float h = acc[n][r] + bb;
      h = h > 0.f ? h : 0.f;
      p[r] += h * w2v;
    }
  }
#pragma unroll
  for (int m = 1; m < 16; m <<= 1) {
#pragma unroll
    for (int r = 0; r < 4; ++r) p[r] += __shfl_xor(p[r], m);
  }
  if (col_l == 0) {
    float b2v = b2[0];
    int rbase = i0 + w * 16 + (l >> 4) * 4;
#pragma unroll
    for (int r = 0; r < 4; ++r) ws[WS_CLSL + rbase + r] = p[r] + b2v;
  }
}

// ================= k_proto: streaming VALU distances + fused epilogue =================
__global__ __launch_bounds__(256, 4) void k_proto(const float* __restrict__ zp,
                                                  const float* __restrict__ ws,
                                                  float* __restrict__ out) {
  __shared__ __align__(16) float pp[4 * DIM];
  __shared__ float pns[4];
  int t = threadIdx.x;
  for (int idx = t; idx < 4 * DIM; idx += 256) pp[idx] = ws[WS_PPROTO + idx];
  if (t < 4) pns[t] = ws[WS_PN + t];
  __syncthreads();

  int w = t >> 6, l = t & 63, s = l & 7, r = l >> 3;
  int i = blockIdx.x * 32 + w * 8 + r;
  const float* xr = zp + (size_t)i * DIM;

  float d0 = 0.f, d1 = 0.f, d2 = 0.f, dn = 0.f, sx = 0.f;
#pragma unroll
  for (int j = 0; j < 16; ++j) {
    int col = j * 32 + s * 4;
    float4 x  = *(const float4*)(xr + col);
    float4 c0 = *(const float4*)(&pp[0 * DIM + col]);
    float4 c1 = *(const float4*)(&pp[1 * DIM + col]);
    float4 c2 = *(const float4*)(&pp[2 * DIM + col]);
    float4 c3 = *(const float4*)(&pp[3 * DIM + col]);
    d0 += x.x * c0.x + x.y * c0.y + x.z * c0.z + x.w * c0.w;
    d1 += x.x * c1.x + x.y * c1.y + x.z * c1.z + x.w * c1.w;
    d2 += x.x * c2.x + x.y * c2.y + x.z * c2.z + x.w * c2.w;
    dn += x.x * c3.x + x.y * c3.y + x.z * c3.z + x.w * c3.w;
    sx += x.x * x.x  + x.y * x.y  + x.z * x.z  + x.w * x.w;
  }
#pragma unroll
  for (int m = 1; m < 8; m <<= 1) {
    d0 += __shfl_xor(d0, m);
    d1 += __shfl_xor(d1, m);
    d2 += __shfl_xor(d2, m);
    dn += __shfl_xor(dn, m);
    sx += __shfl_xor(sx, m);
  }
  if (s == 0) {
    float e0 = sx + pns[0] - 2.f * d0; e0 = fmaxf(e0, 0.f);
    float e1 = sx + pns[1] - 2.f * d1; e1 = fmaxf(e1, 0.f);
    float e2 = sx + pns[2] - 2.f * d2; e2 = fmaxf(e2, 0.f);
    float dpos = e0; int a = 0;
    if (e1 < dpos) { dpos = e1; a = 1; }
    if (e2 < dpos) { dpos = e2; a = 2; }
    float dneg = (sx + pns[3] - 2.f * dn) * (1.f / DIM);
    float plog = (dneg - dpos) * 0.04419417382415922f;   // 1/sqrt(512)
    float o2 = 0.2f * plog;
    float lg = (ws[WS_CLSL + i] + o2) * 0.4f;            // /2.5
    float prob = 1.f / (1.f + expf(-lg));
    out[i]            = lg;
    out[NPTS + i]     = prob;
    out[2 * NPTS + i] = o2;
    out[3 * NPTS + i] = (float)a;
    out[4 * NPTS + 3 * i]     = e0;
    out[4 * NPTS + 3 * i + 1] = e1;
    out[4 * NPTS + 3 * i + 2] = e2;
  }
}

extern "C" void kernel_launch(void* const* d_in, const int* in_sizes, int n_in,
                              void* d_out, int out_size, void* d_ws, size_t ws_size,
                              hipStream_t stream) {
  const float* z_cls   = (const float*)d_in[0];
  const float* z_proto = (const float*)d_in[1];
  const float* pos_ctx = (const float*)d_in[2];
  const float* neg_ctx = (const float*)d_in[3];
  const float* W1      = (const float*)d_in[4];
  const float* b1      = (const float*)d_in[5];
  const float* W2      = (const float*)d_in[6];
  const float* b2      = (const float*)d_in[7];
  const float* Wp      = (const float*)d_in[8];
  const float* bp      = (const float*)d_in[9];
  const float* Wn      = (const float*)d_in[10];
  const float* bn      = (const float*)d_in[11];
  const int* pos_idx   = (const int*)d_in[12];
  const int* neg_idx   = (const int*)d_in[13];
  float* out           = (float*)d_out;
  float* ws            = (float*)d_ws;

  k_prep<<<321, 256, 0, stream>>>(W1, Wp, bp, Wn, bn, pos_ctx, neg_ctx, z_proto, neg_idx, ws);
  k_km<0><<<257, 256, 0, stream>>>(z_proto, pos_idx, ws);
  k_km<1><<<256, 256, 0, stream>>>(z_proto, pos_idx, ws);
  k_km<2><<<256, 256, 0, stream>>>(z_proto, pos_idx, ws);
  k_km<3><<<256, 256, 0, stream>>>(z_proto, pos_idx, ws);
  k_fin<<<1, 256, 0, stream>>>(z_proto, pos_idx, ws, out);
  k_cls<<<NPTS / 64, 256, 0, stream>>>(z_cls, b1, W2, b2, ws);
  k_proto<<<NPTS / 32, 256, 0, stream>>>(z_proto, ws, out);
}